// Round 7
// baseline (217.173 us; speedup 1.0000x reference)
//
#include <hip/hip_runtime.h>
#include <hip/hip_bf16.h>

#define Bn   8
#define Cn   64
#define Nn   40962
#define Kn   7
#define OUTn 64
#define NVT32  1281   // 32-vertex tiles per batch
#define GROUPS 160    // persistent groups per batch (8 x 160 = 1280 blocks, 5/CU)
// flattened K dim = Kn*Cn = 448 = 14 chunks of 32

typedef __bf16 bf16x8 __attribute__((ext_vector_type(8)));
typedef __bf16 bf16x4 __attribute__((ext_vector_type(4)));
typedef float  f32x4  __attribute__((ext_vector_type(4)));

// ---------------------------------------------------------------------------
// Pass 1: transpose+convert x [B, C, N] f32 -> xT [B, N, C] bf16.
// (held constant -- ~33 us vs 20 us traffic floor; not this round's lever)
// ---------------------------------------------------------------------------
__global__ __launch_bounds__(256) void transpose_kernel(
    const float* __restrict__ x, __bf16* __restrict__ xT,
    const float* __restrict__ W, __bf16* __restrict__ Wb, int b0)
{
    __shared__ unsigned int tile[64][65];   // [c][n-pair slot]; +1 pad
    const int tid  = threadIdx.x;
    const int lane = tid & 63;
    const int w    = tid >> 6;
    const int n0   = blockIdx.x * 128;
    const int bl   = blockIdx.y;
    const int b    = b0 + bl;
    const size_t xb = (size_t)b * Cn * Nn;

    // fused convw: first 112 blocks of bl==0 slice cover 28672 W elements
    if (bl == 0) {
        const int wi = blockIdx.x * 256 + tid;
        if (wi < OUTn * Kn * Cn) Wb[wi] = (__bf16)W[wi];
    }

    const int n = n0 + lane * 2;
    if (n < Nn) {
#pragma unroll
        for (int i = 0; i < 16; ++i) {
            const int c = w * 16 + i;
            const float2 v = *(const float2*)(x + xb + (size_t)c * Nn + n);
            const unsigned short ua =
                __builtin_bit_cast(unsigned short, (__bf16)v.x);
            const unsigned short ub =
                __builtin_bit_cast(unsigned short, (__bf16)v.y);
            tile[c][lane] = ((unsigned)ub << 16) | (unsigned)ua;
        }
    }
    __syncthreads();

    const int rsub = lane >> 3;
    const int cblk = lane & 7;
#pragma unroll
    for (int it = 0; it < 4; ++it) {
        const int row = it * 32 + w * 8 + rsub;
        const int n1  = n0 + row;
        if (n1 < Nn) {
            const int slot = row >> 1;
            const int sh   = (row & 1) * 16;
            bf16x8 frag;
#pragma unroll
            for (int e = 0; e < 8; ++e) {
                const unsigned u = tile[cblk * 8 + e][slot];
                frag[e] = __builtin_bit_cast(
                    __bf16, (unsigned short)((u >> sh) & 0xffffu));
            }
            *(bf16x8*)(xT + ((size_t)bl * Nn + n1) * Cn + cblk * 8) = frag;
        }
    }
}

// ---------------------------------------------------------------------------
// Pass 2 v8: v5 skeleton at 5 blocks/CU.
// Ledger: all-at-once staging + 2 barriers/tile = REAL (-21us); everything
// that only re-timed waits within the 2-blocks/CU regime (depth-3 vmcnt,
// ds-read halving, tile-level double-buffer) = null/negative. The untested
// lever is CONCURRENCY: with 2 stage/compute streams per CU, the CU idles
// whenever both blocks are in their stage phase (stage latency >> compute).
// v8: 32-vertex tile -> sbuf = 7x32x64x2B = 28.7 KB -> 5 blocks/CU
// (143.4 of 160 KB LDS), grid 1280 persistent blocks; each tile's exposed
// stage latency is covered by 4 other resident blocks in staggered phases.
// Wave w owns output strip s=w (16 outputs) x all 32 vertices: aW[14] =
// 56 VGPR, total fits the 102-VGPR cap of 5 waves/SIMD
// (__launch_bounds__(256,5)); the 4x cross-wave ds_read duplication this
// reintroduces was proven null in v6. Staging: wave stages rows
// [8w, 8w+8): 7 fire-and-forget gll/wave. XOR source-permutation and
// reader slot = q^(col&7) unchanged (conflict-free rounds 1-6).
// blk&7 = batch = XCD.
// ---------------------------------------------------------------------------
__global__ __launch_bounds__(256, 5) void gconv_kernel(
    const __bf16* __restrict__ xT,    // [B, N, C] bf16
    const int*    __restrict__ nbr,   // [N*7] int32
    const __bf16* __restrict__ Wb,    // [64, 448] bf16
    const float*  __restrict__ bias,  // [64] f32
    float*        __restrict__ out)   // [B, 64, N] f32
{
    __shared__ __bf16 sbuf[Kn][32][64];   // 28672 B: [kn][vertex row][c]

    const int blk  = blockIdx.x;
    const int bl   = blk & 7;         // batch == XCD
    const int grp  = blk >> 3;        // 0..159 within batch
    const int w    = threadIdx.x >> 6;   // wave id == output strip s
    const int l    = threadIdx.x & 63;
    const int col  = l & 15;
    const int quad = l >> 4;
    const int rme  = l >> 3;          // row within this wave's 8-row stripe
    const int srcoff = ((l & 7) ^ rme) * 16;   // chunk-permuted source
    const __bf16* xb = xT + (size_t)bl * Nn * Cn;

    // ---- A fragments: W rows w*16+col, all 14 k-chunks, once per block ----
    bf16x8 aW[14];
#pragma unroll
    for (int kc = 0; kc < 14; ++kc)
        aW[kc] = *(const bf16x8*)(Wb + (size_t)(w * 16 + col) * (Kn * Cn)
                                     + kc * 32 + quad * 8);

    float bv[4];
#pragma unroll
    for (int r4 = 0; r4 < 4; ++r4)
        bv[r4] = bias[w * 16 + quad * 4 + r4];

    // offsets for the ONE row this lane stages (tile row = w*8 + rme)
#define LOADIDX(vt_, dst_)                                                    \
    {                                                                         \
        int v = (vt_)*32 + w * 8 + rme;                                       \
        if (v > Nn - 1) v = Nn - 1;                                           \
        _Pragma("unroll")                                                     \
        for (int kn = 0; kn < Kn; ++kn) {                                     \
            int id = nbr[v * 7 + kn];                                         \
            id = id < 0 ? 0 : (id >= Nn ? Nn - 1 : id);                       \
            dst_[kn] = id * (Cn * 2);                                         \
        }                                                                     \
    }

    int ofsA[Kn];
    LOADIDX(grp, ofsA)

    for (int vt = grp; vt < NVT32; vt += GROUPS) {
        __syncthreads();   // WAR: prev tile's laggard ds_reads done before restage

        // ---- stage all 7 kn (7 fire-and-forget global_load_lds / wave) ----
#pragma unroll
        for (int kn = 0; kn < Kn; ++kn) {
            const char* src_ = (const char*)xb + ofsA[kn] + srcoff;
            __builtin_amdgcn_global_load_lds(
                (const unsigned int*)src_,
                (unsigned int*)&sbuf[kn][w * 8][0], 16, 0, 0);
        }

        // ---- prefetch next tile's indices under the stage latency ----
        int ofsB[Kn];
        LOADIDX(vt + GROUPS, ofsB)   // clamped internally; wasted on last iter

        __syncthreads();   // vmcnt(0)+barrier: every wave's stages landed

        // ---- compute: 28 ds_read_b128 + 28 MFMA per wave ----
        f32x4 acc[2];
        acc[0] = (f32x4){0.f, 0.f, 0.f, 0.f};
        acc[1] = (f32x4){0.f, 0.f, 0.f, 0.f};

        __builtin_amdgcn_s_setprio(1);
#pragma unroll
        for (int kn = 0; kn < Kn; ++kn) {
#pragma unroll
            for (int h = 0; h < 2; ++h) {
                const int q = h * 4 + quad;
#pragma unroll
                for (int t = 0; t < 2; ++t) {
                    const int r    = t * 16 + col;
                    const int slot = q ^ (col & 7);
                    const bf16x8 bf = *(const bf16x8*)&sbuf[kn][r][slot * 8];
                    acc[t] = __builtin_amdgcn_mfma_f32_16x16x32_bf16(
                        aW[kn * 2 + h], bf, acc[t], 0, 0, 0);
                }
            }
        }
        __builtin_amdgcn_s_setprio(0);

        // ---- epilogue: col -> vertex, quad*4+r4 -> o ----
        const int v0 = vt * 32;
#pragma unroll
        for (int r4 = 0; r4 < 4; ++r4) {
            const int o = w * 16 + quad * 4 + r4;
#pragma unroll
            for (int t = 0; t < 2; ++t) {
                const int n = v0 + t * 16 + col;
                if (n < Nn)
                    out[((size_t)bl * OUTn + o) * Nn + n] = acc[t][r4] + bv[r4];
            }
        }

#pragma unroll
        for (int kn = 0; kn < Kn; ++kn)
            ofsA[kn] = ofsB[kn];
    }
#undef LOADIDX
}

// ---------------------------------------------------------------------------
// Fallback: no workspace needed. Pure f32. Slow but correct.
// ---------------------------------------------------------------------------
__global__ __launch_bounds__(256) void naive_kernel(
    const float* __restrict__ x, const int* __restrict__ nbr,
    const float* __restrict__ W, const float* __restrict__ bias,
    float* __restrict__ out)
{
    __shared__ float xs[4][Kn * Cn];
    const int v = threadIdx.x >> 6;
    const int o = threadIdx.x & 63;
    const int b = blockIdx.y;
    const int n = blockIdx.x * 4 + v;
    const bool ok = n < Nn;
    const int nn = ok ? n : 0;

#pragma unroll
    for (int k = 0; k < Kn; ++k) {
        int id = nbr[nn * Kn + k];
        id = id < 0 ? 0 : (id >= Nn ? Nn - 1 : id);
        xs[v][k * Cn + o] = x[((size_t)b * Cn + o) * Nn + id];
    }
    __syncthreads();

    float acc = bias[o];
    for (int j = 0; j < Kn * Cn; ++j)
        acc += W[o * (Kn * Cn) + j] * xs[v][j];

    if (ok)
        out[((size_t)b * OUTn + o) * Nn + n] = acc;
}

extern "C" void kernel_launch(void* const* d_in, const int* in_sizes, int n_in,
                              void* d_out, int out_size, void* d_ws, size_t ws_size,
                              hipStream_t stream)
{
    const float* x    = (const float*)d_in[0];
    const int*   nbr  = (const int*)d_in[1];
    const float* W    = (const float*)d_in[2];
    const float* bias = (const float*)d_in[3];
    float*       out  = (float*)d_out;

    const size_t w_bytes     = (size_t)OUTn * Kn * Cn * sizeof(__bf16); // 57344
    const size_t batch_bytes = (size_t)Nn * Cn * sizeof(__bf16);        // 5.24 MB
    int nb = 0;
    if (ws_size > w_bytes)
        nb = (int)((ws_size - w_bytes) / batch_bytes);
    if (nb > Bn) nb = Bn;

    if (nb >= Bn) {
        __bf16* Wb = (__bf16*)d_ws;
        __bf16* xT = (__bf16*)((char*)d_ws + w_bytes);

        dim3 tgrid((Nn + 127) / 128, Bn);
        transpose_kernel<<<tgrid, 256, 0, stream>>>(x, xT, W, Wb, 0);
        gconv_kernel<<<Bn * GROUPS, 256, 0, stream>>>(xT, nbr, Wb, bias, out);
    } else {
        dim3 ngrid((Nn + 3) / 4, Bn);
        naive_kernel<<<ngrid, 256, 0, stream>>>(x, nbr, W, bias, out);
    }
}

// Round 9
// 196.789 us; speedup vs baseline: 1.1036x; 1.1036x over previous
//
#include <hip/hip_runtime.h>
#include <hip/hip_bf16.h>

#define Bn   8
#define Cn   64
#define Nn   40962
#define Kn   7
#define OUTn 64
#define NVT  641      // 64-vertex tiles per batch
// flattened K dim = Kn*Cn = 448 = 14 chunks of 32

typedef __bf16 bf16x8 __attribute__((ext_vector_type(8)));
typedef __bf16 bf16x4 __attribute__((ext_vector_type(4)));
typedef float  f32x4  __attribute__((ext_vector_type(4)));

// ---------------------------------------------------------------------------
// Pass 1: transpose+convert x [B, C, N] f32 -> xT [B, N, C] bf16.
// (held constant -- ~33 us vs 20 us traffic floor; control)
// ---------------------------------------------------------------------------
__global__ __launch_bounds__(256) void transpose_kernel(
    const float* __restrict__ x, __bf16* __restrict__ xT,
    const float* __restrict__ W, __bf16* __restrict__ Wb, int b0)
{
    __shared__ unsigned int tile[64][65];   // [c][n-pair slot]; +1 pad
    const int tid  = threadIdx.x;
    const int lane = tid & 63;
    const int w    = tid >> 6;
    const int n0   = blockIdx.x * 128;
    const int bl   = blockIdx.y;
    const int b    = b0 + bl;
    const size_t xb = (size_t)b * Cn * Nn;

    // fused convw: first 112 blocks of bl==0 slice cover 28672 W elements
    if (bl == 0) {
        const int wi = blockIdx.x * 256 + tid;
        if (wi < OUTn * Kn * Cn) Wb[wi] = (__bf16)W[wi];
    }

    const int n = n0 + lane * 2;
    if (n < Nn) {
#pragma unroll
        for (int i = 0; i < 16; ++i) {
            const int c = w * 16 + i;
            const float2 v = *(const float2*)(x + xb + (size_t)c * Nn + n);
            const unsigned short ua =
                __builtin_bit_cast(unsigned short, (__bf16)v.x);
            const unsigned short ub =
                __builtin_bit_cast(unsigned short, (__bf16)v.y);
            tile[c][lane] = ((unsigned)ub << 16) | (unsigned)ua;
        }
    }
    __syncthreads();

    const int rsub = lane >> 3;
    const int cblk = lane & 7;
#pragma unroll
    for (int it = 0; it < 4; ++it) {
        const int row = it * 32 + w * 8 + rsub;
        const int n1  = n0 + row;
        if (n1 < Nn) {
            const int slot = row >> 1;
            const int sh   = (row & 1) * 16;
            bf16x8 frag;
#pragma unroll
            for (int e = 0; e < 8; ++e) {
                const unsigned u = tile[cblk * 8 + e][slot];
                frag[e] = __builtin_bit_cast(
                    __bf16, (unsigned short)((u >> sh) & 0xffffu));
            }
            *(bf16x8*)(xT + ((size_t)bl * Nn + n1) * Cn + cblk * 8) = frag;
        }
    }
}

// ---------------------------------------------------------------------------
// Pass 2 v10: round-4 kernel (proven stable, 56.5 us) + NON-TEMPORAL out
// stores. Theory: the gather stream (293 MB random 128-B rows) is serviced
// from L3/HBM because the per-XCD L2 (4 MB) is 1.3x oversubscribed by the
// 5.25 MB batch slice AND continuously thrashed by the 95 MB out store
// stream (~12 MB/XCD of write-once lines). NT stores keep out lines out of
// L2 -> higher gather hit rate -> shorter stage drains (the only lever
// that has ever moved this kernel). Everything else byte-identical to
// round 4: 512 persistent blocks (blk&7 = batch = XCD), aW once per block,
// all-7-kn fire-and-forget staging, 2 barriers/tile, XOR source
// permutation (conflict-free rounds 1-7).
// ---------------------------------------------------------------------------
__global__ __launch_bounds__(256, 2) void gconv_kernel(
    const __bf16* __restrict__ xT,    // [B, N, C] bf16
    const int*    __restrict__ nbr,   // [N*7] int32
    const __bf16* __restrict__ Wb,    // [64, 448] bf16
    const float*  __restrict__ bias,  // [64] f32
    float*        __restrict__ out)   // [B, 64, N] f32
{
    __shared__ __bf16 sbuf[Kn][64][64];   // 57344 B: [kn][vertex row][c]

    const int blk  = blockIdx.x;
    const int bl   = blk & 7;         // batch == XCD
    const int grp  = blk >> 3;        // 0..63 within batch
    const int w    = threadIdx.x >> 6;
    const int l    = threadIdx.x & 63;
    const int col  = l & 15;
    const int quad = l >> 4;
    const int rme  = l >> 3;
    const int srcoff = ((l & 7) ^ rme) * 16;
    const __bf16* xb = xT + (size_t)bl * Nn * Cn;

    // ---- A fragments: W rows w*16+col, all 14 k-chunks, once per block ----
    bf16x8 aW[14];
#pragma unroll
    for (int kc = 0; kc < 14; ++kc)
        aW[kc] = *(const bf16x8*)(Wb + (size_t)(w * 16 + col) * (Kn * Cn)
                                     + kc * 32 + quad * 8);

    const float bv[4] = {bias[w * 16 + quad * 4 + 0],
                         bias[w * 16 + quad * 4 + 1],
                         bias[w * 16 + quad * 4 + 2],
                         bias[w * 16 + quad * 4 + 3]};

    // neighbor byte-offsets for the rows this lane stages (rows w*16+j*8+rme)
#define LOADIDX(vt_, dst_)                                                    \
    {                                                                         \
        _Pragma("unroll")                                                     \
        for (int j = 0; j < 2; ++j) {                                         \
            int v = (vt_)*64 + w * 16 + j * 8 + rme;                          \
            if (v > Nn - 1) v = Nn - 1;                                       \
            _Pragma("unroll")                                                 \
            for (int kn = 0; kn < Kn; ++kn) {                                 \
                int id = nbr[v * 7 + kn];                                     \
                id = id < 0 ? 0 : (id >= Nn ? Nn - 1 : id);                   \
                dst_[j][kn] = id * (Cn * 2);                                  \
            }                                                                 \
        }                                                                     \
    }

    int ofsA[2][Kn];
    LOADIDX(grp, ofsA)

    for (int vt = grp; vt < NVT; vt += 64) {
        __syncthreads();   // WAR: prev tile's laggard ds_reads done before restage

        // ---- stage ALL 7 kn (14 fire-and-forget global_load_lds / wave) ----
#pragma unroll
        for (int kn = 0; kn < Kn; ++kn) {
#pragma unroll
            for (int j = 0; j < 2; ++j) {
                const char* src_ = (const char*)xb + ofsA[j][kn] + srcoff;
                __builtin_amdgcn_global_load_lds(
                    (const unsigned int*)src_,
                    (unsigned int*)&sbuf[kn][w * 16 + j * 8][0], 16, 0, 0);
            }
        }

        // ---- prefetch next tile's indices under the stage latency ----
        int ofsB[2][Kn];
        LOADIDX(vt + 64, ofsB)       // clamped internally; wasted on last iter

        __syncthreads();   // vmcnt(0)+barrier: every wave's stages landed

        // ---- compute: 56 ds_read_b128 + 56 MFMA, no waits in between ----
        f32x4 acc[4];
#pragma unroll
        for (int t = 0; t < 4; ++t)
            acc[t] = (f32x4){0.f, 0.f, 0.f, 0.f};

        __builtin_amdgcn_s_setprio(1);
#pragma unroll
        for (int kn = 0; kn < Kn; ++kn) {
#pragma unroll
            for (int h = 0; h < 2; ++h) {
                const int q = h * 4 + quad;
#pragma unroll
                for (int t = 0; t < 4; ++t) {
                    const int r    = t * 16 + col;
                    const int slot = q ^ (r & 7);
                    const bf16x8 bf = *(const bf16x8*)&sbuf[kn][r][slot * 8];
                    acc[t] = __builtin_amdgcn_mfma_f32_16x16x32_bf16(
                        aW[kn * 2 + h], bf, acc[t], 0, 0, 0);
                }
            }
        }
        __builtin_amdgcn_s_setprio(0);

        // ---- epilogue: NON-TEMPORAL stores (write-once, never re-read;
        //      keep these 95 MB/dispatch out of the gather-critical L2) ----
        const int v0 = vt * 64;
#pragma unroll
        for (int r4 = 0; r4 < 4; ++r4) {
            const int o = w * 16 + quad * 4 + r4;
#pragma unroll
            for (int t = 0; t < 4; ++t) {
                const int n = v0 + t * 16 + col;
                if (n < Nn)
                    __builtin_nontemporal_store(
                        acc[t][r4] + bv[r4],
                        &out[((size_t)bl * OUTn + o) * Nn + n]);
            }
        }

#pragma unroll
        for (int j = 0; j < 2; ++j)
#pragma unroll
            for (int kn = 0; kn < Kn; ++kn)
                ofsA[j][kn] = ofsB[j][kn];
    }
#undef LOADIDX
}

// ---------------------------------------------------------------------------
// Fallback: no workspace needed. Pure f32. Slow but correct.
// ---------------------------------------------------------------------------
__global__ __launch_bounds__(256) void naive_kernel(
    const float* __restrict__ x, const int* __restrict__ nbr,
    const float* __restrict__ W, const float* __restrict__ bias,
    float* __restrict__ out)
{
    __shared__ float xs[4][Kn * Cn];
    const int v = threadIdx.x >> 6;
    const int o = threadIdx.x & 63;
    const int b = blockIdx.y;
    const int n = blockIdx.x * 4 + v;
    const bool ok = n < Nn;
    const int nn = ok ? n : 0;

#pragma unroll
    for (int k = 0; k < Kn; ++k) {
        int id = nbr[nn * Kn + k];
        id = id < 0 ? 0 : (id >= Nn ? Nn - 1 : id);
        xs[v][k * Cn + o] = x[((size_t)b * Cn + o) * Nn + id];
    }
    __syncthreads();

    float acc = bias[o];
    for (int j = 0; j < Kn * Cn; ++j)
        acc += W[o * (Kn * Cn) + j] * xs[v][j];

    if (ok)
        out[((size_t)b * OUTn + o) * Nn + n] = acc;
}

extern "C" void kernel_launch(void* const* d_in, const int* in_sizes, int n_in,
                              void* d_out, int out_size, void* d_ws, size_t ws_size,
                              hipStream_t stream)
{
    const float* x    = (const float*)d_in[0];
    const int*   nbr  = (const int*)d_in[1];
    const float* W    = (const float*)d_in[2];
    const float* bias = (const float*)d_in[3];
    float*       out  = (float*)d_out;

    const size_t w_bytes     = (size_t)OUTn * Kn * Cn * sizeof(__bf16); // 57344
    const size_t batch_bytes = (size_t)Nn * Cn * sizeof(__bf16);        // 5.24 MB
    int nb = 0;
    if (ws_size > w_bytes)
        nb = (int)((ws_size - w_bytes) / batch_bytes);
    if (nb > Bn) nb = Bn;

    if (nb >= Bn) {
        __bf16* Wb = (__bf16*)d_ws;
        __bf16* xT = (__bf16*)((char*)d_ws + w_bytes);

        dim3 tgrid((Nn + 127) / 128, Bn);
        transpose_kernel<<<tgrid, 256, 0, stream>>>(x, xT, W, Wb, 0);
        gconv_kernel<<<512, 256, 0, stream>>>(xT, nbr, Wb, bias, out);
    } else {
        dim3 ngrid((Nn + 3) / 4, Bn);
        naive_kernel<<<ngrid, 256, 0, stream>>>(x, nbr, W, bias, out);
    }
}